// Round 5
// baseline (823.252 us; speedup 1.0000x reference)
//
#include <hip/hip_runtime.h>
#include <math.h>

#define NN 100000
#define DD 128
#define OUT_DIM 256
#define HOPS 3
#define EDGES 640000
#define TGT (HOPS*NN)          // 300000

typedef short bf16x8 __attribute__((ext_vector_type(8)));
typedef float f32x4 __attribute__((ext_vector_type(4)));

__device__ __forceinline__ unsigned short f2bf(float f) {
    unsigned u = __float_as_uint(f);
    unsigned r = u + 0x7FFFu + ((u >> 16) & 1u);   // RNE
    return (unsigned short)(r >> 16);
}
__device__ __forceinline__ float bf2f(unsigned short s) {
    return __uint_as_float(((unsigned)s) << 16);
}
__device__ __forceinline__ float silu(float v) { return v / (1.0f + expf(-v)); }

// XOR-swizzle on element index within a row of a bf16 activation/weight
// buffer: permutes 16B slots inside each 64-elem (128B) chunk by row&7.
// Involution; baked into global storage so global_load_lds stays linear
// (rule: swizzle both-sides-or-neither).
__device__ __forceinline__ int swz(int c, int r) {
    return (c & ~63) | ((c & 63) ^ ((r & 7) << 3));
}

__device__ __forceinline__ void gload16(const unsigned short* g, unsigned short* l) {
    __builtin_amdgcn_global_load_lds(
        (const __attribute__((address_space(1))) void*)g,
        (__attribute__((address_space(3))) void*)l, 16, 0, 0);
}

// ---------------------------------------------------------------------------
// CSR build: histogram -> block scan -> partial scan -> add-back -> fill
// ---------------------------------------------------------------------------
__global__ __launch_bounds__(256) void k_hist(const int* __restrict__ tgt,
                                              int* __restrict__ cnt) {
    int e = blockIdx.x * 256 + threadIdx.x;
    atomicAdd(&cnt[tgt[e]], 1);
}

__global__ __launch_bounds__(512) void k_scanb(const int* __restrict__ cnt,
                                               int* __restrict__ off,
                                               int* __restrict__ part, int n) {
    __shared__ int s[512];
    int tid = threadIdx.x;
    int g = blockIdx.x * 512 + tid;
    int v = (g < n) ? cnt[g] : 0;
    s[tid] = v;
    __syncthreads();
    for (int d = 1; d < 512; d <<= 1) {
        int a = (tid >= d) ? s[tid - d] : 0;
        __syncthreads();
        s[tid] += a;
        __syncthreads();
    }
    if (g < n) off[g] = s[tid] - v;                  // exclusive
    if (tid == 511) part[blockIdx.x] = s[511];
}

__global__ __launch_bounds__(1024) void k_scanp(int* __restrict__ part, int n) {
    __shared__ int s[1024];
    int t = threadIdx.x;
    s[t] = (t < n) ? part[t] : 0;
    __syncthreads();
    for (int d = 1; d < 1024; d <<= 1) {
        int a = (t >= d) ? s[t - d] : 0;
        __syncthreads();
        s[t] += a;
        __syncthreads();
    }
    if (t < n) part[t] = s[t];                       // inclusive
}

__global__ __launch_bounds__(512) void k_addoff(int* __restrict__ off,
                                                const int* __restrict__ part,
                                                int* __restrict__ cursor, int n) {
    int g = blockIdx.x * 512 + threadIdx.x;
    if (g >= n) return;
    int add = (blockIdx.x > 0) ? part[blockIdx.x - 1] : 0;
    int o = off[g] + add;
    off[g] = o;
    cursor[g] = o;
}

__global__ __launch_bounds__(256) void k_fill(const int* __restrict__ tgt,
                                              const int* __restrict__ src,
                                              int* __restrict__ cursor,
                                              int* __restrict__ esrc) {
    int e = blockIdx.x * 256 + threadIdx.x;
    int t = tgt[e];
    int p = atomicAdd(&cursor[t], 1);
    esrc[p] = src[e] % NN;
}

// ---------------------------------------------------------------------------
// Gather-aggregate + feats build (bf16, PRE-SWIZZLED layout).
// One 64-lane wave per virtual row; each lane handles one 2-elem pair.
// Pair-index swizzle: elem-swz (c&63)^((r&7)<<3)  ->  pair (p&31)^((r&7)<<2).
// ---------------------------------------------------------------------------
__global__ __launch_bounds__(256) void k_aggfeats(const float* __restrict__ x,
                                                  const int* __restrict__ off,
                                                  const int* __restrict__ cur,
                                                  const int* __restrict__ esrc,
                                                  unsigned* __restrict__ feats) {
    int lane = threadIdx.x & 63;
    int r = blockIdx.x * 4 + (threadIdx.x >> 6);
    const float2* x2 = (const float2*)x;
    if (r < NN) {
        float2 v = x2[(size_t)r * 64 + lane];
        int p = lane;                                // pairs 0..63
        int ps = (p & ~31) | ((p & 31) ^ ((r & 7) << 2));
        feats[(size_t)r * 256 + ps] =
            (unsigned)f2bf(v.x) | ((unsigned)f2bf(v.y) << 16);
    } else {
        int t = r - NN;
        int hop = t / NN;
        int tn = t - hop * NN;
        int b = off[t], e = cur[t];
        float ax = 0.f, ay = 0.f;
        for (int i = b; i < e; ++i) {
            int sn = esrc[i];
            float2 v = x2[(size_t)sn * 64 + lane];
            ax += v.x; ay += v.y;
        }
        int p = 64 + hop * 64 + lane;                // pairs 64..255
        int ps = (p & ~31) | ((p & 31) ^ ((tn & 7) << 2));
        feats[(size_t)tn * 256 + ps] =
            (unsigned)f2bf(ax) | ((unsigned)f2bf(ay) << 16);
    }
}

// ---------------------------------------------------------------------------
// Weight prep: bf16 + transpose to Wt[c][k] (LD=K), PRE-SWIZZLED in k.
// ---------------------------------------------------------------------------
__global__ __launch_bounds__(256) void k_wprep(
    const float* __restrict__ Win, const float* __restrict__ Wskip,
    const float* __restrict__ W10, const float* __restrict__ W20,
    const float* __restrict__ W11, const float* __restrict__ W21,
    unsigned short* __restrict__ Wt1, unsigned short* __restrict__ Wt25) {
    int idx = blockIdx.x * 256 + threadIdx.x;        // grid = 2048 blocks
    if (idx < 262144) {
        int c = idx >> 9, k = idx & 511;
        int kl = swz(k, c);                          // logical k stored at slot k
        float v = (c < 256) ? Win[kl * 256 + c] : Wskip[kl * 256 + (c - 256)];
        Wt1[idx] = f2bf(v);
    } else {
        int j = idx - 262144;
        int m = j >> 16, rr = j & 65535;
        int c = rr >> 8, k = rr & 255;
        int kl = swz(k, c);
        const float* Wm = (m == 0) ? W10 : (m == 1) ? W20 : (m == 2) ? W11 : W21;
        Wt25[(size_t)m * 65536 + c * 256 + k] = f2bf(Wm[kl * 256 + c]);
    }
}

// ---------------------------------------------------------------------------
// Tiled MFMA GEMM: BM=128, BN=128, BK=64, 4 waves, 64x64 wave-tile,
// double-buffered LDS with prefetch-before-compute (T3 minimum 2-phase),
// swizzled LDS reads (conflict-free ds_read_b128).
// A[M,K] bf16 row-major pre-swizzled; Wt[N,K] bf16 pre-swizzled.
// EPI: 0: Cb = bf16(silu(v+b0))          (swizzled write)
//      1: Cb = bf16(v + b0 + res1)       (swizzled read+write)
//      2: Cf = v + b0 + res1 + res2      (res1 swizzled, res2/Cf linear f32)
//      3: gemm1 dual: col<256 -> Cb = bf16(silu(v+b0)) swizzled;
//                     col>=256 -> Cf = v+b1 linear f32
// ---------------------------------------------------------------------------
template <int K, int EPI>
__global__ __launch_bounds__(256) void k_gemm_t(
    const unsigned short* __restrict__ A, const unsigned short* __restrict__ Wt,
    const float* __restrict__ bias0, const float* __restrict__ bias1,
    const unsigned short* __restrict__ res1, const float* __restrict__ res2,
    unsigned short* __restrict__ Cb, float* __restrict__ Cf) {
    __shared__ unsigned short As[2][128 * 64];
    __shared__ unsigned short Bs[2][128 * 64];

    const int tid = threadIdx.x;
    const int lane = tid & 63;
    const int w = tid >> 6;
    const int row0 = blockIdx.x * 128;
    const int col0 = blockIdx.y * 128;

    const int wr = (w >> 1) * 64;
    const int wc = (w & 1) * 64;
    const int lr = lane & 15;
    const int lk8 = (lane >> 4) * 8;

    f32x4 acc[4][4];
    #pragma unroll
    for (int m = 0; m < 4; ++m)
        #pragma unroll
        for (int n = 0; n < 4; ++n) acc[m][n] = (f32x4){0.f, 0.f, 0.f, 0.f};

    const int NK = K / 64;

    auto STAGE = [&](int buf, int k0) {
        #pragma unroll
        for (int i = 0; i < 4; ++i) {
            int chunk = i * 4 + w;                   // wave-uniform
            int slot = chunk * 64 + lane;
            int r = slot >> 3;                       // 0..127
            int kq = (slot & 7) * 8;                 // 0..56
            gload16(A + (size_t)(row0 + r) * K + k0 + kq, &As[buf][chunk * 512]);
            gload16(Wt + (size_t)(col0 + r) * K + k0 + kq, &Bs[buf][chunk * 512]);
        }
    };

    STAGE(0, 0);
    asm volatile("s_waitcnt vmcnt(0)" ::: "memory");
    __syncthreads();

    for (int ks = 0; ks < NK; ++ks) {
        int cur = ks & 1;
        if (ks + 1 < NK) STAGE(cur ^ 1, (ks + 1) * 64);   // prefetch next tile

        #pragma unroll
        for (int ks2 = 0; ks2 < 2; ++ks2) {
            bf16x8 af[4], bfr[4];
            #pragma unroll
            for (int m = 0; m < 4; ++m) {
                int row = wr + m * 16 + lr;
                int eo = (ks2 * 32 + lk8) ^ ((row & 7) << 3);
                af[m] = *(const bf16x8*)&As[cur][row * 64 + eo];
            }
            #pragma unroll
            for (int n = 0; n < 4; ++n) {
                int row = wc + n * 16 + lr;
                int eo = (ks2 * 32 + lk8) ^ ((row & 7) << 3);
                bfr[n] = *(const bf16x8*)&Bs[cur][row * 64 + eo];
            }
            #pragma unroll
            for (int m = 0; m < 4; ++m)
                #pragma unroll
                for (int n = 0; n < 4; ++n)
                    acc[m][n] = __builtin_amdgcn_mfma_f32_16x16x32_bf16(
                        af[m], bfr[n], acc[m][n], 0, 0, 0);
        }
        asm volatile("s_waitcnt vmcnt(0)" ::: "memory");  // next tile landed
        __syncthreads();
    }

    const int rq = (lane >> 4) * 4;
    #pragma unroll
    for (int m = 0; m < 4; ++m) {
        #pragma unroll
        for (int n = 0; n < 4; ++n) {
            int cg = col0 + wc + n * 16 + lr;        // global col
            float bb = (EPI == 3)
                           ? (cg < OUT_DIM ? bias0[cg] : bias1[cg - OUT_DIM])
                           : bias0[cg];
            #pragma unroll
            for (int j = 0; j < 4; ++j) {
                int r = row0 + wr + m * 16 + rq + j;
                if (r >= NN) continue;
                float v = acc[m][n][j] + bb;
                if (EPI == 3) {
                    if (cg < OUT_DIM)
                        Cb[(size_t)r * OUT_DIM + swz(cg, r)] = f2bf(silu(v));
                    else
                        Cf[(size_t)r * OUT_DIM + (cg - OUT_DIM)] = v;
                } else if (EPI == 0) {
                    Cb[(size_t)r * OUT_DIM + swz(cg, r)] = f2bf(silu(v));
                } else if (EPI == 1) {
                    size_t o = (size_t)r * OUT_DIM + swz(cg, r);
                    Cb[o] = f2bf(v + bf2f(res1[o]));
                } else {
                    size_t os = (size_t)r * OUT_DIM + swz(cg, r);
                    size_t ol = (size_t)r * OUT_DIM + cg;
                    Cf[ol] = v + bf2f(res1[os]) + res2[ol];
                }
            }
        }
    }
}

extern "C" void kernel_launch(void* const* d_in, const int* in_sizes, int n_in,
                              void* d_out, int out_size, void* d_ws, size_t ws_size,
                              hipStream_t stream) {
    const float* x      = (const float*)d_in[0];
    const int*   target = (const int*)d_in[1];
    const int*   src    = (const int*)d_in[2];
    const float* W_in   = (const float*)d_in[3];
    const float* b_in   = (const float*)d_in[4];
    const float* W1_0   = (const float*)d_in[5];
    const float* b1_0   = (const float*)d_in[6];
    const float* W2_0   = (const float*)d_in[7];
    const float* b2_0   = (const float*)d_in[8];
    const float* W1_1   = (const float*)d_in[9];
    const float* b1_1   = (const float*)d_in[10];
    const float* W2_1   = (const float*)d_in[11];
    const float* b2_1   = (const float*)d_in[12];
    const float* W_skip = (const float*)d_in[13];
    const float* b_skip = (const float*)d_in[14];
    float* out = (float*)d_out;

    // workspace layout
    char* p = (char*)d_ws;
    unsigned short* feats = (unsigned short*)p; p += (size_t)NN * 512 * 2;   // 102.4 MB
    unsigned short* h0    = (unsigned short*)p; p += (size_t)NN * 256 * 2;   // 51.2 MB
    unsigned short* h1    = (unsigned short*)p; p += (size_t)NN * 256 * 2;
    unsigned short* tb    = (unsigned short*)p; p += (size_t)NN * 256 * 2;
    unsigned short* Wt1   = (unsigned short*)p; p += 512 * 512 * 2;
    unsigned short* Wt25  = (unsigned short*)p; p += 4 * 256 * 256 * 2;
    int* cnt    = (int*)p; p += (size_t)TGT * 4;
    int* off    = (int*)p; p += (size_t)TGT * 4;
    int* cursor = (int*)p; p += (size_t)TGT * 4;
    int* esrc   = (int*)p; p += (size_t)EDGES * 4;
    int* part   = (int*)p; p += 4096;

    const int SCAN_BLOCKS = (TGT + 511) / 512;        // 586

    // CSR build
    hipMemsetAsync(cnt, 0, (size_t)TGT * 4, stream);
    k_hist<<<EDGES / 256, 256, 0, stream>>>(target, cnt);
    k_scanb<<<SCAN_BLOCKS, 512, 0, stream>>>(cnt, off, part, TGT);
    k_scanp<<<1, 1024, 0, stream>>>(part, SCAN_BLOCKS);
    k_addoff<<<SCAN_BLOCKS, 512, 0, stream>>>(off, part, cursor, TGT);
    k_fill<<<EDGES / 256, 256, 0, stream>>>(target, src, cursor, esrc);

    // gather-aggregate + bf16 feats build (pre-swizzled)
    k_aggfeats<<<NN, 256, 0, stream>>>(x, off, cursor, esrc, (unsigned*)feats);

    // weight prep (pre-swizzled)
    k_wprep<<<2048, 256, 0, stream>>>(W_in, W_skip, W1_0, W2_0, W1_1, W2_1,
                                      Wt1, Wt25);

    const int GM = (NN + 127) / 128;                  // 782

    // GEMM1: cols 0-255 -> h0 = silu(feats@W_in+b) bf16; cols 256-511 -> gskip f32
    k_gemm_t<512, 3><<<dim3(GM, 4), 256, 0, stream>>>(
        feats, Wt1, b_in, b_skip, nullptr, nullptr, h0, out);

    // residual block 0
    k_gemm_t<256, 0><<<dim3(GM, 2), 256, 0, stream>>>(
        h0, Wt25 + 0 * 65536, b1_0, nullptr, nullptr, nullptr, tb, nullptr);
    k_gemm_t<256, 1><<<dim3(GM, 2), 256, 0, stream>>>(
        tb, Wt25 + 1 * 65536, b2_0, nullptr, h0, nullptr, h1, nullptr);

    // residual block 1, final fuse (+h1 residual + gskip already in d_out)
    k_gemm_t<256, 0><<<dim3(GM, 2), 256, 0, stream>>>(
        h1, Wt25 + 2 * 65536, b1_1, nullptr, nullptr, nullptr, tb, nullptr);
    k_gemm_t<256, 2><<<dim3(GM, 2), 256, 0, stream>>>(
        tb, Wt25 + 3 * 65536, b2_1, nullptr, h1, out, nullptr, out);
}

// Round 8
// 696.879 us; speedup vs baseline: 1.1813x; 1.1813x over previous
//
#include <hip/hip_runtime.h>
#include <math.h>

#define NN 100000
#define DD 128
#define OUT_DIM 256
#define HOPS 3
#define EDGES 640000
#define TGT (HOPS*NN)          // 300000

typedef short bf16x8 __attribute__((ext_vector_type(8)));
typedef float f32x4 __attribute__((ext_vector_type(4)));

__device__ __forceinline__ unsigned short f2bf(float f) {
    unsigned u = __float_as_uint(f);
    unsigned r = u + 0x7FFFu + ((u >> 16) & 1u);   // RNE
    return (unsigned short)(r >> 16);
}
__device__ __forceinline__ float bf2f(unsigned short s) {
    return __uint_as_float(((unsigned)s) << 16);
}
__device__ __forceinline__ float silu(float v) { return v / (1.0f + expf(-v)); }

// XOR-swizzle on element index within 64-elem (128B) chunks keyed by row&7.
// Involution; baked into global bf16 activation/weight buffers so
// global_load_lds stays linear (both-sides-or-neither rule).
__device__ __forceinline__ int swz(int c, int r) {
    return (c & ~63) | ((c & 63) ^ ((r & 7) << 3));
}

__device__ __forceinline__ void gload16(const unsigned short* g, unsigned short* l) {
    __builtin_amdgcn_global_load_lds(
        (const __attribute__((address_space(1))) void*)g,
        (__attribute__((address_space(3))) void*)l, 16, 0, 0);
}

// ---------------------------------------------------------------------------
// CSR build: histogram -> block scan -> partial scan -> add-back -> fill
// ---------------------------------------------------------------------------
__global__ __launch_bounds__(256) void k_hist(const int* __restrict__ tgt,
                                              int* __restrict__ cnt) {
    int e = blockIdx.x * 256 + threadIdx.x;
    atomicAdd(&cnt[tgt[e]], 1);
}

__global__ __launch_bounds__(512) void k_scanb(const int* __restrict__ cnt,
                                               int* __restrict__ off,
                                               int* __restrict__ part, int n) {
    __shared__ int s[512];
    int tid = threadIdx.x;
    int g = blockIdx.x * 512 + tid;
    int v = (g < n) ? cnt[g] : 0;
    s[tid] = v;
    __syncthreads();
    for (int d = 1; d < 512; d <<= 1) {
        int a = (tid >= d) ? s[tid - d] : 0;
        __syncthreads();
        s[tid] += a;
        __syncthreads();
    }
    if (g < n) off[g] = s[tid] - v;                  // exclusive
    if (tid == 511) part[blockIdx.x] = s[511];
}

__global__ __launch_bounds__(1024) void k_scanp(int* __restrict__ part, int n) {
    __shared__ int s[1024];
    int t = threadIdx.x;
    s[t] = (t < n) ? part[t] : 0;
    __syncthreads();
    for (int d = 1; d < 1024; d <<= 1) {
        int a = (t >= d) ? s[t - d] : 0;
        __syncthreads();
        s[t] += a;
        __syncthreads();
    }
    if (t < n) part[t] = s[t];                       // inclusive
}

__global__ __launch_bounds__(512) void k_addoff(int* __restrict__ off,
                                                const int* __restrict__ part,
                                                int* __restrict__ cursor, int n) {
    int g = blockIdx.x * 512 + threadIdx.x;
    if (g >= n) return;
    int add = (blockIdx.x > 0) ? part[blockIdx.x - 1] : 0;
    int o = off[g] + add;
    off[g] = o;
    cursor[g] = o;
}

__global__ __launch_bounds__(256) void k_fill(const int* __restrict__ tgt,
                                              const int* __restrict__ src,
                                              int* __restrict__ cursor,
                                              int* __restrict__ esrc) {
    int e = blockIdx.x * 256 + threadIdx.x;
    int t = tgt[e];
    int p = atomicAdd(&cursor[t], 1);
    esrc[p] = src[e] % NN;
}

// ---------------------------------------------------------------------------
// Gather-aggregate + feats build (bf16, PRE-SWIZZLED layout).
// ---------------------------------------------------------------------------
__global__ __launch_bounds__(256) void k_aggfeats(const float* __restrict__ x,
                                                  const int* __restrict__ off,
                                                  const int* __restrict__ cur,
                                                  const int* __restrict__ esrc,
                                                  unsigned* __restrict__ feats) {
    int lane = threadIdx.x & 63;
    int r = blockIdx.x * 4 + (threadIdx.x >> 6);
    const float2* x2 = (const float2*)x;
    if (r < NN) {
        float2 v = x2[(size_t)r * 64 + lane];
        int p = lane;                                // pairs 0..63
        int ps = (p & ~31) | ((p & 31) ^ ((r & 7) << 2));
        feats[(size_t)r * 256 + ps] =
            (unsigned)f2bf(v.x) | ((unsigned)f2bf(v.y) << 16);
    } else {
        int t = r - NN;
        int hop = t / NN;
        int tn = t - hop * NN;
        int b = off[t], e = cur[t];
        float ax = 0.f, ay = 0.f;
        for (int i = b; i < e; ++i) {
            int sn = esrc[i];
            float2 v = x2[(size_t)sn * 64 + lane];
            ax += v.x; ay += v.y;
        }
        int p = 64 + hop * 64 + lane;                // pairs 64..255
        int ps = (p & ~31) | ((p & 31) ^ ((tn & 7) << 2));
        feats[(size_t)tn * 256 + ps] =
            (unsigned)f2bf(ax) | ((unsigned)f2bf(ay) << 16);
    }
}

// ---------------------------------------------------------------------------
// Weight prep: bf16 + transpose to Wt[c][k] (LD=K), PRE-SWIZZLED in k.
// ---------------------------------------------------------------------------
__global__ __launch_bounds__(256) void k_wprep(
    const float* __restrict__ Win, const float* __restrict__ Wskip,
    const float* __restrict__ W10, const float* __restrict__ W20,
    const float* __restrict__ W11, const float* __restrict__ W21,
    unsigned short* __restrict__ Wt1, unsigned short* __restrict__ Wt25) {
    int idx = blockIdx.x * 256 + threadIdx.x;        // grid = 2048 blocks
    if (idx < 262144) {
        int c = idx >> 9, k = idx & 511;
        int kl = swz(k, c);                          // logical k stored at slot k
        float v = (c < 256) ? Win[kl * 256 + c] : Wskip[kl * 256 + (c - 256)];
        Wt1[idx] = f2bf(v);
    } else {
        int j = idx - 262144;
        int m = j >> 16, rr = j & 65535;
        int c = rr >> 8, k = rr & 255;
        int kl = swz(k, c);
        const float* Wm = (m == 0) ? W10 : (m == 1) ? W20 : (m == 2) ? W11 : W21;
        Wt25[(size_t)m * 65536 + c * 256 + k] = f2bf(Wm[kl * 256 + c]);
    }
}

// ---------------------------------------------------------------------------
// GEMM1: feats[N,512]swz @ Wt1[512c][512k]swz. BM=BN=128, BK=64, 4 waves,
// dbuf LDS + prefetch. cols 0-255 -> h0 = bf16 silu (swz); 256-511 -> gsk bf16 linear.
// ---------------------------------------------------------------------------
__global__ __launch_bounds__(256) void k_gemm1(
    const unsigned short* __restrict__ A, const unsigned short* __restrict__ Wt,
    const float* __restrict__ bias0, const float* __restrict__ bias1,
    unsigned short* __restrict__ h0, unsigned short* __restrict__ gsk) {
    const int K = 512;
    __shared__ unsigned short As[2][128 * 64];
    __shared__ unsigned short Bs[2][128 * 64];

    const int tid = threadIdx.x;
    const int lane = tid & 63;
    const int w = tid >> 6;
    const int row0 = blockIdx.x * 128;
    const int col0 = blockIdx.y * 128;

    const int wr = (w >> 1) * 64;
    const int wc = (w & 1) * 64;
    const int lr = lane & 15;
    const int lk8 = (lane >> 4) * 8;

    f32x4 acc[4][4];
    #pragma unroll
    for (int m = 0; m < 4; ++m)
        #pragma unroll
        for (int n = 0; n < 4; ++n) acc[m][n] = (f32x4){0.f, 0.f, 0.f, 0.f};

    auto STAGE = [&](int buf, int k0) {
        #pragma unroll
        for (int i = 0; i < 4; ++i) {
            int chunk = i * 4 + w;                   // wave-uniform
            int slot = chunk * 64 + lane;
            int r = slot >> 3;                       // 0..127
            int kq = (slot & 7) * 8;                 // 0..56
            gload16(A + (size_t)(row0 + r) * K + k0 + kq, &As[buf][chunk * 512]);
            gload16(Wt + (size_t)(col0 + r) * K + k0 + kq, &Bs[buf][chunk * 512]);
        }
    };

    STAGE(0, 0);
    asm volatile("s_waitcnt vmcnt(0)" ::: "memory");
    __syncthreads();

    for (int ks = 0; ks < 8; ++ks) {
        int cur = ks & 1;
        if (ks + 1 < 8) STAGE(cur ^ 1, (ks + 1) * 64);

        #pragma unroll
        for (int ks2 = 0; ks2 < 2; ++ks2) {
            bf16x8 af[4], bfr[4];
            #pragma unroll
            for (int m = 0; m < 4; ++m) {
                int row = wr + m * 16 + lr;
                int eo = (ks2 * 32 + lk8) ^ ((row & 7) << 3);
                af[m] = *(const bf16x8*)&As[cur][row * 64 + eo];
            }
            #pragma unroll
            for (int n = 0; n < 4; ++n) {
                int row = wc + n * 16 + lr;
                int eo = (ks2 * 32 + lk8) ^ ((row & 7) << 3);
                bfr[n] = *(const bf16x8*)&Bs[cur][row * 64 + eo];
            }
            #pragma unroll
            for (int m = 0; m < 4; ++m)
                #pragma unroll
                for (int n = 0; n < 4; ++n)
                    acc[m][n] = __builtin_amdgcn_mfma_f32_16x16x32_bf16(
                        af[m], bfr[n], acc[m][n], 0, 0, 0);
        }
        asm volatile("s_waitcnt vmcnt(0)" ::: "memory");
        __syncthreads();
    }

    const int rq = (lane >> 4) * 4;
    #pragma unroll
    for (int m = 0; m < 4; ++m) {
        #pragma unroll
        for (int n = 0; n < 4; ++n) {
            int cg = col0 + wc + n * 16 + lr;        // 0..511
            float bb = (cg < OUT_DIM) ? bias0[cg] : bias1[cg - OUT_DIM];
            #pragma unroll
            for (int j = 0; j < 4; ++j) {
                int r = row0 + wr + m * 16 + rq + j;
                if (r >= NN) continue;
                float v = acc[m][n][j] + bb;
                if (cg < OUT_DIM)
                    h0[(size_t)r * OUT_DIM + swz(cg, r)] = f2bf(silu(v));
                else
                    gsk[(size_t)r * OUT_DIM + (cg - OUT_DIM)] = f2bf(v);
            }
        }
    }
}

// ---------------------------------------------------------------------------
// Fused residual MLP block: Hout = silu(Hin@W1+b1)@W2 + b2 + Hin  [+ gsk]
// BM=128 rows/block, full N=256, K=256. 8 waves (512 thr), wave-tile 32x128.
// LDS: Hs 64 KB (Hin panel, later overwritten by t) + Ws dbuf 2x32 KB = 128 KB.
// Residual folded into acc2 init from Hs before t overwrites it.
// W tiles chained: W1 k0..k3 then W2 k0..k3 through the same dbuf.
// FINAL=0: write bf16 swz Hout.  FINAL=1: write f32 linear out + gsk(bf16).
// ---------------------------------------------------------------------------
template <int FINAL>
__global__ __launch_bounds__(512) void k_mlp(
    const unsigned short* __restrict__ Hin,
    const unsigned short* __restrict__ W1t, const unsigned short* __restrict__ W2t,
    const float* __restrict__ b1, const float* __restrict__ b2,
    const unsigned short* __restrict__ gsk,
    unsigned short* __restrict__ Hout, float* __restrict__ outf) {
    __shared__ unsigned short Hs[128 * 256];         // 64 KB
    __shared__ unsigned short Ws[2][256 * 64];       // 64 KB

    const int tid = threadIdx.x;
    const int lane = tid & 63;
    const int w = tid >> 6;                          // 0..7
    const int wr = (w >> 1) * 32;
    const int wc = (w & 1) * 128;
    const int lr = lane & 15;
    const int lk8 = (lane >> 4) * 8;
    const int row0 = blockIdx.x * 128;

    auto STAGE_W = [&](const unsigned short* Wt, int buf, int ks) {
        #pragma unroll
        for (int i = 0; i < 4; ++i) {
            int chunk = w * 4 + i;                   // 0..31, wave-uniform
            int col = chunk * 8 + (lane >> 3);
            int ko = ks * 64 + (lane & 7) * 8;
            gload16(Wt + (size_t)col * 256 + ko, &Ws[buf][chunk * 512]);
        }
    };

    // stage Hin panel (64 KB) + first W1 tile
    #pragma unroll
    for (int i = 0; i < 8; ++i) {
        int chunk = w * 8 + i;                       // 0..63, wave-uniform
        gload16(Hin + (size_t)row0 * 256 + chunk * 512 + lane * 8,
                &Hs[chunk * 512]);
    }
    STAGE_W(W1t, 0, 0);
    asm volatile("s_waitcnt vmcnt(0)" ::: "memory");
    __syncthreads();

    f32x4 acc_t[2][8];
    #pragma unroll
    for (int m = 0; m < 2; ++m)
        #pragma unroll
        for (int n = 0; n < 8; ++n) acc_t[m][n] = (f32x4){0.f, 0.f, 0.f, 0.f};

    // ---- GEMM A: t = Hin @ W1  (silu+b1 applied at t-write)
    for (int ks = 0; ks < 4; ++ks) {
        if (ks < 3) STAGE_W(W1t, (ks + 1) & 1, ks + 1);
        else        STAGE_W(W2t, 0, 0);             // chain into GEMM B
        #pragma unroll
        for (int ks2 = 0; ks2 < 2; ++ks2) {
            bf16x8 af[2], bfr[8];
            #pragma unroll
            for (int m = 0; m < 2; ++m) {
                int row = wr + m * 16 + lr;
                int eo = (ks2 * 32 + lk8) ^ ((row & 7) << 3);
                af[m] = *(const bf16x8*)&Hs[row * 256 + ks * 64 + eo];
            }
            #pragma unroll
            for (int n = 0; n < 8; ++n) {
                int col = wc + n * 16 + lr;
                int eo = (ks2 * 32 + lk8) ^ ((col & 7) << 3);
                bfr[n] = *(const bf16x8*)&Ws[ks & 1][col * 64 + eo];
            }
            #pragma unroll
            for (int m = 0; m < 2; ++m)
                #pragma unroll
                for (int n = 0; n < 8; ++n)
                    acc_t[m][n] = __builtin_amdgcn_mfma_f32_16x16x32_bf16(
                        af[m], bfr[n], acc_t[m][n], 0, 0, 0);
        }
        asm volatile("s_waitcnt vmcnt(0)" ::: "memory");
        __syncthreads();
    }

    // ---- acc2 = Hin(residual) + b2, read from Hs before overwrite
    const int rq = (lane >> 4) * 4;
    f32x4 acc2[2][8];
    #pragma unroll
    for (int m = 0; m < 2; ++m)
        #pragma unroll
        for (int n = 0; n < 8; ++n) {
            int col = wc + n * 16 + lr;
            float bb = b2[col];
            #pragma unroll
            for (int j = 0; j < 4; ++j) {
                int row = wr + m * 16 + rq + j;
                int sc = (col & ~63) | ((col & 63) ^ ((row & 7) << 3));
                acc2[m][n][j] = bf2f(Hs[row * 256 + sc]) + bb;
            }
        }
    __syncthreads();                                 // all residual reads done

    // ---- t = bf16(silu(acc_t + b1)) overwrites Hs
    #pragma unroll
    for (int m = 0; m < 2; ++m)
        #pragma unroll
        for (int n = 0; n < 8; ++n) {
            int col = wc + n * 16 + lr;
            float bb = b1[col];
            #pragma unroll
            for (int j = 0; j < 4; ++j) {
                int row = wr + m * 16 + rq + j;
                int sc = (col & ~63) | ((col & 63) ^ ((row & 7) << 3));
                Hs[row * 256 + sc] = f2bf(silu(acc_t[m][n][j] + bb));
            }
        }
    __syncthreads();                                 // t visible to all waves

    // ---- GEMM B: acc2 += t @ W2
    for (int ks = 0; ks < 4; ++ks) {
        if (ks < 3) STAGE_W(W2t, (ks + 1) & 1, ks + 1);
        #pragma unroll
        for (int ks2 = 0; ks2 < 2; ++ks2) {
            bf16x8 af[2], bfr[8];
            #pragma unroll
            for (int m = 0; m < 2; ++m) {
                int row = wr + m * 16 + lr;
                int eo = (ks2 * 32 + lk8) ^ ((row & 7) << 3);
                af[m] = *(const bf16x8*)&Hs[row * 256 + ks * 64 + eo];
            }
            #pragma unroll
            for (int n = 0; n < 8; ++n) {
                int col = wc + n * 16 + lr;
                int eo = (ks2 * 32 + lk8) ^ ((col & 7) << 3);
                bfr[n] = *(const bf16x8*)&Ws[ks & 1][col * 64 + eo];
            }
            #pragma unroll
            for (int m = 0; m < 2; ++m)
                #pragma unroll
                for (int n = 0; n < 8; ++n)
                    acc2[m][n] = __builtin_amdgcn_mfma_f32_16x16x32_bf16(
                        af[m], bfr[n], acc2[m][n], 0, 0, 0);
        }
        asm volatile("s_waitcnt vmcnt(0)" ::: "memory");
        __syncthreads();
    }

    // ---- epilogue
    #pragma unroll
    for (int m = 0; m < 2; ++m)
        #pragma unroll
        for (int n = 0; n < 8; ++n) {
            int col = wc + n * 16 + lr;
            #pragma unroll
            for (int j = 0; j < 4; ++j) {
                int row = wr + m * 16 + rq + j;
                int r = row0 + row;
                if (r >= NN) continue;
                if (FINAL == 0) {
                    Hout[(size_t)r * 256 + swz(col, row)] = f2bf(acc2[m][n][j]);
                } else {
                    size_t o = (size_t)r * 256 + col;
                    outf[o] = acc2[m][n][j] + bf2f(gsk[o]);
                }
            }
        }
}

extern "C" void kernel_launch(void* const* d_in, const int* in_sizes, int n_in,
                              void* d_out, int out_size, void* d_ws, size_t ws_size,
                              hipStream_t stream) {
    const float* x      = (const float*)d_in[0];
    const int*   target = (const int*)d_in[1];
    const int*   src    = (const int*)d_in[2];
    const float* W_in   = (const float*)d_in[3];
    const float* b_in   = (const float*)d_in[4];
    const float* W1_0   = (const float*)d_in[5];
    const float* b1_0   = (const float*)d_in[6];
    const float* W2_0   = (const float*)d_in[7];
    const float* b2_0   = (const float*)d_in[8];
    const float* W1_1   = (const float*)d_in[9];
    const float* b1_1   = (const float*)d_in[10];
    const float* W2_1   = (const float*)d_in[11];
    const float* b2_1   = (const float*)d_in[12];
    const float* W_skip = (const float*)d_in[13];
    const float* b_skip = (const float*)d_in[14];
    float* out = (float*)d_out;

    // workspace layout
    char* p = (char*)d_ws;
    unsigned short* feats = (unsigned short*)p; p += (size_t)NN * 512 * 2;   // 102.4 MB
    unsigned short* h0    = (unsigned short*)p; p += (size_t)NN * 256 * 2;   // 51.2 MB
    unsigned short* h1    = (unsigned short*)p; p += (size_t)NN * 256 * 2;
    unsigned short* gsk   = (unsigned short*)p; p += (size_t)NN * 256 * 2;
    unsigned short* Wt1   = (unsigned short*)p; p += 512 * 512 * 2;
    unsigned short* Wt25  = (unsigned short*)p; p += 4 * 256 * 256 * 2;
    int* cnt    = (int*)p; p += (size_t)TGT * 4;
    int* off    = (int*)p; p += (size_t)TGT * 4;
    int* cursor = (int*)p; p += (size_t)TGT * 4;
    int* esrc   = (int*)p; p += (size_t)EDGES * 4;
    int* part   = (int*)p; p += 4096;

    const int SCAN_BLOCKS = (TGT + 511) / 512;        // 586

    // CSR build
    hipMemsetAsync(cnt, 0, (size_t)TGT * 4, stream);
    k_hist<<<EDGES / 256, 256, 0, stream>>>(target, cnt);
    k_scanb<<<SCAN_BLOCKS, 512, 0, stream>>>(cnt, off, part, TGT);
    k_scanp<<<1, 1024, 0, stream>>>(part, SCAN_BLOCKS);
    k_addoff<<<SCAN_BLOCKS, 512, 0, stream>>>(off, part, cursor, TGT);
    k_fill<<<EDGES / 256, 256, 0, stream>>>(target, src, cursor, esrc);

    // gather-aggregate + bf16 feats build (pre-swizzled)
    k_aggfeats<<<NN, 256, 0, stream>>>(x, off, cursor, esrc, (unsigned*)feats);

    // weight prep (pre-swizzled)
    k_wprep<<<2048, 256, 0, stream>>>(W_in, W_skip, W1_0, W2_0, W1_1, W2_1,
                                      Wt1, Wt25);

    const int GM = (NN + 127) / 128;                  // 782

    // GEMM1: h0 = silu(feats@W_in+b) swz bf16; gsk = feats@W_skip+b linear bf16
    k_gemm1<<<dim3(GM, 4), 256, 0, stream>>>(feats, Wt1, b_in, b_skip, h0, gsk);

    // fused residual block 0: h1 = silu(h0@W1_0+b1)@W2_0 + b2 + h0
    k_mlp<0><<<GM, 512, 0, stream>>>(h0, Wt25 + 0 * 65536, Wt25 + 1 * 65536,
                                     b1_0, b2_0, nullptr, h1, nullptr);
    // fused residual block 1 + gskip: out = silu(h1@W1_1+b1)@W2_1 + b2 + h1 + gsk
    k_mlp<1><<<GM, 512, 0, stream>>>(h1, Wt25 + 2 * 65536, Wt25 + 3 * 65536,
                                     b1_1, b2_1, gsk, nullptr, out);
}